// Round 6
// baseline (1429.926 us; speedup 1.0000x reference)
//
#include <hip/hip_runtime.h>
#include <hip/hip_bf16.h>

// ---------------------------------------------------------------------------
// SpMiddlePillarEncoder8x18. Round 6: halo conv fixed — double-buffered halo
// (2x36,864B LDS -> 2 blocks/CU -> 256-VGPR budget, no spill), single-depth
// B-register fragments, stage(cc+1) issued at tap 4 (in-order-vmcnt-aware
// placement), padded epilogue transpose (stride 66). Gather pillar, XCD
// swizzle, zero-page OOB redirect kept. Stride-2 layer keeps round-4 kernel.
// ---------------------------------------------------------------------------

typedef __attribute__((ext_vector_type(8))) short bf16x8;
typedef __attribute__((ext_vector_type(4))) float f32x4;
typedef unsigned short u16;

#define GLD16(g, l)                                                   \
    __builtin_amdgcn_global_load_lds(                                 \
        (const __attribute__((address_space(1))) void*)(g),           \
        (__attribute__((address_space(3))) void*)(l), 16, 0, 0)

__device__ __forceinline__ u16 f2b(float f) {
    unsigned u = __float_as_uint(f);
    u += 0x7fffu + ((u >> 16) & 1u);  // round-to-nearest-even
    return (u16)(u >> 16);
}
__device__ __forceinline__ float b2f(u16 h) {
    return __uint_as_float(((unsigned)h) << 16);
}

// ------------------------------- binning -----------------------------------
__global__ __launch_bounds__(256) void bin_kernel(
    const float* __restrict__ xyz, const int* __restrict__ cnt,
    int* __restrict__ pcnt, int* __restrict__ plist, int N) {
    int i = blockIdx.x * 256 + threadIdx.x;
    if (i >= N) return;
    float x = xyz[3 * i], y = xyz[3 * i + 1];
    int b = (i < cnt[0]) ? 0 : 1;
    int ix = (int)floorf((x + 75.2f) / 0.8f);
    int iy = (int)floorf((y + 75.2f) / 0.8f);
    ix = min(max(ix, 0), 187);
    iy = min(max(iy, 0), 187);
    int flat = (b * 188 + iy) * 188 + ix;
    int slot = atomicAdd(pcnt + flat, 1);
    if (slot < 32) plist[flat * 32 + slot] = i;
}

// --------------------------- pillar MLP + max ------------------------------
__global__ __launch_bounds__(256) void pillar_kernel(
    const float* __restrict__ xyz, const float* __restrict__ ptf,
    const float* __restrict__ mw, const float* __restrict__ mg,
    const float* __restrict__ mb, const int* __restrict__ pcnt,
    const int* __restrict__ plist, u16* __restrict__ out,
    float* __restrict__ occ) {
    const int lane = threadIdx.x & 63, wid = threadIdx.x >> 6;
    const int p = blockIdx.x * 4 + wid;
    const int n = min(pcnt[p], 32);
    const int c = lane * 4;
    float m0 = 0.f, m1 = 0.f, m2 = 0.f, m3 = 0.f;
    if (n > 0) {
        const int ix = p % 188;
        const int iy = (p / 188) % 188;
        const float cx = -75.2f + ((float)ix + 0.5f) * 0.8f;
        const float cy = -75.2f + ((float)iy + 0.5f) * 0.8f;
        float4 w[8];
#pragma unroll
        for (int k = 0; k < 8; k++) w[k] = *(const float4*)(mw + k * 256 + c);
        for (int t = 0; t < n; t++) {
            int i = __builtin_amdgcn_readfirstlane(plist[p * 32 + t]);
            float x = xyz[3 * i], y = xyz[3 * i + 1], z = xyz[3 * i + 2];
            float f0 = ptf[2 * i], f1 = ptf[2 * i + 1];
            const float f[8] = {x, y, z, x - cx, y - cy, z, f0, f1};
            float s0 = 0.f, s1 = 0.f, s2 = 0.f, s3 = 0.f;
#pragma unroll
            for (int k = 0; k < 8; k++) {
                s0 = fmaf(f[k], w[k].x, s0);
                s1 = fmaf(f[k], w[k].y, s1);
                s2 = fmaf(f[k], w[k].z, s2);
                s3 = fmaf(f[k], w[k].w, s3);
            }
            float4 g4 = *(const float4*)(mg + c);
            float4 b4 = *(const float4*)(mb + c);
            m0 = fmaxf(m0, fmaxf(s0 * g4.x + b4.x, 0.f));
            m1 = fmaxf(m1, fmaxf(s1 * g4.y + b4.y, 0.f));
            m2 = fmaxf(m2, fmaxf(s2 * g4.z + b4.z, 0.f));
            m3 = fmaxf(m3, fmaxf(s3 * g4.w + b4.w, 0.f));
        }
    }
    unsigned lo = (unsigned)f2b(m0) | ((unsigned)f2b(m1) << 16);
    unsigned hi = (unsigned)f2b(m2) | ((unsigned)f2b(m3) << 16);
    *(uint2*)(out + (size_t)p * 256 + c) = make_uint2(lo, hi);
    if (lane == 0) occ[p] = (n > 0) ? 1.f : 0.f;
}

// -------------------- weight convert+transpose (once/launch) ---------------
__global__ void cvt_weights_kernel(const float* __restrict__ w4,
                                   const float* __restrict__ w5,
                                   u16* __restrict__ wt4,
                                   u16* __restrict__ wt5) {
    int bid = blockIdx.x;
    int mat = bid >> 4;
    int tile = bid & 15;
    int tr = tile >> 2, tc = tile & 3;
    const float* src = (mat < 45) ? (w4 + (size_t)mat * 65536)
                                  : (w5 + (size_t)(mat - 45) * 65536);
    u16* dst = (mat < 45) ? (wt4 + (size_t)mat * 65536)
                          : (wt5 + (size_t)(mat - 45) * 65536);
    __shared__ u16 sm[64][65];
    int tx = threadIdx.x & 63, ty = threadIdx.x >> 6;
#pragma unroll
    for (int k = 0; k < 64; k += 4) {
        int c = tr * 64 + ty + k;
        int n = tc * 64 + tx;
        sm[tx][ty + k] = f2b(src[c * 256 + n]);
    }
    __syncthreads();
#pragma unroll
    for (int k = 0; k < 64; k += 4) {
        int n = tc * 64 + ty + k;
        int c = tr * 64 + tx;
        dst[n * 256 + c] = sm[ty + k][tx];
    }
}

// --------------------- halo-staged 3x3 conv (stride 1) ---------------------
// Block: 2 out rows x 64 out cols x 128 out-ch, 4 waves (wr=row, wc=ch-half).
// Double-buffered halo [4][72][64] (2x36,864B). Per chunk: 9 taps x
// (8 A ds_read_b128 + 32 MFMA + 8 B reg loads); stage(cc+1) issued at t==4;
// one vmcnt(0)+barrier per chunk.
template <bool HAS_MASK, bool HAS_RES, bool HAS_F32OUT>
__global__ __launch_bounds__(256, 2) void conv3x3_halo_kernel(
    const u16* __restrict__ in,    // [2*H*W, 256] bf16 NHWC
    const u16* __restrict__ wt,    // [9][256(n)][256(c)] bf16
    const u16* __restrict__ zeros, // 512B zero page
    const float* __restrict__ gamma, const float* __restrict__ beta,
    const float* __restrict__ mask, const u16* __restrict__ res,
    u16* __restrict__ outb, float* __restrict__ outf,
    int H, int W, int tx, int ty) {
    const int tid = threadIdx.x;
    const int lane = tid & 63, wid = tid >> 6;
    const int wr = wid >> 1, wc = wid & 1;
    const int rA = lane & 15, kq = lane >> 4;

    // bijective XCD-chunked swizzle (m204)
    const int nwg = gridDim.x;
    const int q = nwg >> 3, r = nwg & 7;
    const int xcd = blockIdx.x & 7, jj = blockIdx.x >> 3;
    int wg = (xcd < r ? xcd * (q + 1) : r * (q + 1) + (xcd - r) * q) + jj;
    const int nh = wg & 1;
    int t2 = wg >> 1;
    const int txi = t2 % tx;
    t2 /= tx;
    const int tyi = t2 % ty;
    const int bimg = t2 / ty;
    const int x0 = txi * 64, y0 = tyi * 2, n0 = nh * 128;

    __shared__ u16 SMEM[36864];  // 73,728 B: 2 x [4][72][64] halo buffers

    // staging precompute: granule g = i*256+tid -> (row r, col c, 16B chunk
    // k8). Source chunk swizzled: k8s = k8 ^ (c&7). OOB -> zero page.
    const u16* sbase[9];
#pragma unroll
    for (int i = 0; i < 9; i++) {
        int g = i * 256 + tid;
        int rr_ = g / 576;
        int rem = g - rr_ * 576;
        int c_ = rem >> 3;
        int k8 = rem & 7;
        int yi = y0 - 1 + rr_;
        int xi = x0 - 1 + c_;
        bool ok = (yi >= 0) && (yi < H) && (xi >= 0) && (xi < W);
        int k8s = (k8 ^ (c_ & 7)) * 8;
        sbase[i] = ok ? in + ((size_t)(bimg * H + yi) * W + xi) * 256 + k8s
                      : zeros + k8s;
    }
    // B row pointers: wave covers out-ch n0+wc*64 .. +64
    const u16* bptr[4];
#pragma unroll
    for (int nf = 0; nf < 4; nf++)
        bptr[nf] = wt + (size_t)(n0 + wc * 64 + nf * 16 + rA) * 256 + kq * 8;

    f32x4 acc[4][4];
#pragma unroll
    for (int m = 0; m < 4; m++)
#pragma unroll
        for (int n = 0; n < 4; n++) acc[m][n] = (f32x4)0.f;

    bf16x8 bfr[8];
    // prologue: B(0,0) first (older), then stage(0) -> buf0
#pragma unroll
    for (int nf = 0; nf < 4; nf++)
#pragma unroll
        for (int kh = 0; kh < 2; kh++)
            bfr[nf * 2 + kh] = *(const bf16x8*)(bptr[nf] + kh * 32);
#pragma unroll
    for (int i = 0; i < 9; i++)
        GLD16(sbase[i], SMEM + (i * 256 + wid * 64) * 8);
    asm volatile("s_waitcnt vmcnt(0)" ::: "memory");
    __builtin_amdgcn_sched_barrier(0);
    __builtin_amdgcn_s_barrier();

#pragma unroll 1
    for (int cc = 0; cc < 4; cc++) {
        const u16* cur = SMEM + (cc & 1) * 18432;
        u16* nxt = SMEM + ((cc + 1) & 1) * 18432;
#pragma unroll
        for (int t = 0; t < 9; t++) {
            const int dy = t / 3 - 1, dx = t % 3 - 1;
            bf16x8 af[4][2];
#pragma unroll
            for (int m = 0; m < 4; m++) {
                int hc = m * 16 + rA + 1 + dx;
                int rowb = (((wr + 1 + dy) * 72 + hc) << 6);
                int xv = hc & 7;
#pragma unroll
                for (int kh = 0; kh < 2; kh++)
                    af[m][kh] = *(const bf16x8*)(
                        cur + rowb + (((kh << 2) + kq) ^ xv) * 8);
            }
            __builtin_amdgcn_s_setprio(1);
#pragma unroll
            for (int kh = 0; kh < 2; kh++)
#pragma unroll
                for (int m = 0; m < 4; m++)
#pragma unroll
                    for (int nf = 0; nf < 4; nf++)
                        acc[m][nf] = __builtin_amdgcn_mfma_f32_16x16x32_bf16(
                            af[m][kh], bfr[nf * 2 + kh], acc[m][nf], 0, 0, 0);
            __builtin_amdgcn_s_setprio(0);
            // next B fragments: (cc, t+1) or (cc+1, 0)
            {
                const int off =
                    (t < 8) ? ((t + 1) * 65536 + cc * 64) : ((cc + 1) * 64);
#pragma unroll
                for (int nf = 0; nf < 4; nf++)
#pragma unroll
                    for (int kh = 0; kh < 2; kh++)
                        bfr[nf * 2 + kh] =
                            *(const bf16x8*)(bptr[nf] + off + kh * 32);
            }
            // halo stage for next chunk, issued mid-chunk (t==4): B-loads of
            // taps 0..4 are older (no forced drain); cover = taps 5..8.
            if (t == 4 && cc < 3) {
#pragma unroll
                for (int i = 0; i < 9; i++)
                    GLD16(sbase[i] + (cc + 1) * 64,
                          nxt + (i * 256 + wid * 64) * 8);
            }
        }
        asm volatile("s_waitcnt vmcnt(0)" ::: "memory");
        __builtin_amdgcn_sched_barrier(0);
        __builtin_amdgcn_s_barrier();
    }

    // ---------------- epilogue via LDS transpose (stride-66 pad) ------------
    float* ep = (float*)SMEM + wid * 2112;  // 32 px x 66 f32 per wave
    const int cb = n0 + wc * 64;
    const int row = y0 + wr;
    const size_t gprow = (size_t)(bimg * H + row) * W;
    float gms[4], bts[4];
#pragma unroll
    for (int n = 0; n < 4; n++) {
        gms[n] = gamma[cb + n * 16 + rA];
        bts[n] = beta[cb + n * 16 + rA];
    }
#pragma unroll
    for (int half = 0; half < 2; half++) {
#pragma unroll
        for (int m2 = 0; m2 < 2; m2++) {
            const int m = half * 2 + m2;
            const int lrb = m2 * 16 + (kq << 2);
#pragma unroll
            for (int rr = 0; rr < 4; rr++) {
                const int col = x0 + half * 32 + lrb + rr;
                float mk = 1.f;
                if (HAS_MASK) mk = (col < W) ? mask[gprow + col] : 0.f;
#pragma unroll
                for (int n = 0; n < 4; n++) {
                    float v = acc[m][n][rr] * gms[n] + bts[n];
                    if (HAS_MASK) v *= mk;
                    ep[(lrb + rr) * 66 + n * 16 + rA] = v;
                }
            }
        }
#pragma unroll
        for (int i = 0; i < 8; i++) {
            const int lr = i * 4 + kq;
            const int col = x0 + half * 32 + lr;
            const size_t gp = gprow + col;
            f32x4 v = *(const f32x4*)(ep + lr * 66 + rA * 4);
            if (HAS_RES && col < W) {
                uint2 rv = *(const uint2*)(res + gp * 256 + cb + rA * 4);
                v[0] += b2f((u16)(rv.x & 0xffff));
                v[1] += b2f((u16)(rv.x >> 16));
                v[2] += b2f((u16)(rv.y & 0xffff));
                v[3] += b2f((u16)(rv.y >> 16));
            }
            v[0] = fmaxf(v[0], 0.f);
            v[1] = fmaxf(v[1], 0.f);
            v[2] = fmaxf(v[2], 0.f);
            v[3] = fmaxf(v[3], 0.f);
            if (HAS_F32OUT) *(f32x4*)(ep + lr * 66 + rA * 4) = v;
            if (col < W) {
                unsigned lo = (unsigned)f2b(v[0]) | ((unsigned)f2b(v[1]) << 16);
                unsigned hi = (unsigned)f2b(v[2]) | ((unsigned)f2b(v[3]) << 16);
                *(uint2*)(outb + gp * 256 + cb + rA * 4) = make_uint2(lo, hi);
            }
        }
        if (HAS_F32OUT) {
#pragma unroll
            for (int i = 0; i < 16; i++) {
                const int lc = i * 4 + kq;
                const int px0 = rA * 2;
                const int col0 = x0 + half * 32 + px0;
                if (col0 < W) {
                    float v0 = ep[px0 * 66 + lc];
                    float v1 = ep[(px0 + 1) * 66 + lc];
                    const int ch = cb + lc;
                    float* o = outf + ((size_t)(bimg * 256 + ch) * H + row) * W + col0;
                    *(float2*)o = make_float2(v0, v1);  // W even: pair valid
                }
            }
        }
    }
}

// --------------- round-4 per-tap conv (kept for the stride-2 layer) --------
template <int STRIDE, bool HAS_MASK, bool HAS_RES, bool HAS_F32OUT>
__global__ __launch_bounds__(256) void conv3x3_kernel(
    const u16* __restrict__ in, const u16* __restrict__ wt,
    const u16* __restrict__ zeros, const float* __restrict__ gamma,
    const float* __restrict__ beta, const float* __restrict__ mask,
    const u16* __restrict__ res, u16* __restrict__ outb,
    float* __restrict__ outf, int Hin, int Win, int Hout, int Wout, int Bn) {
    const int M = Bn * Hout * Wout;
    const int HWo = Hout * Wout;
    const int HWi = Hin * Win;
    const int tid = threadIdx.x;
    const int lane = tid & 63, wid = tid >> 6;
    const int wr = wid >> 1, wc = wid & 1;
    const int nwg = gridDim.x;
    const int q = nwg >> 3, r = nwg & 7;
    const int xc = blockIdx.x & 7, jj = blockIdx.x >> 3;
    const int wg = (xc < r ? xc * (q + 1) : r * (q + 1) + (xc - r) * q) + jj;
    const int m0 = (wg >> 1) * 128;
    const int n0 = (wg & 1) * 128;

    __shared__ u16 SMEM[32768];
    const int lrow = lane >> 3;
    const int csw = (((lane & 7) ^ (lrow & 7)) << 3);

    int ppy[4], ppx[4], ppb[4];
    bool ppo[4];
#pragma unroll
    for (int j = 0; j < 4; j++) {
        int gp = m0 + wid * 32 + j * 8 + lrow;
        ppo[j] = gp < M;
        int g2 = ppo[j] ? gp : 0;
        int b = g2 / HWo;
        int rr = g2 - b * HWo;
        ppy[j] = rr / Wout;
        ppx[j] = rr - ppy[j] * Wout;
        ppb[j] = b;
    }
    int bofs[4];
#pragma unroll
    for (int j = 0; j < 4; j++)
        bofs[j] = (n0 + wid * 32 + j * 8 + lrow) * 256 + csw;

#define MKPTR(dst, T)                                                         \
    do {                                                                      \
        int dy_ = (T) / 3 - 1, dx_ = (T) % 3 - 1;                             \
        _Pragma("unroll") for (int j = 0; j < 4; j++) {                       \
            int sy_ = ppy[j] * STRIDE + dy_;                                  \
            int sx_ = ppx[j] * STRIDE + dx_;                                  \
            bool ok_ = ppo[j] && sy_ >= 0 && sy_ < Hin && sx_ >= 0 &&         \
                       sx_ < Win;                                             \
            long long off_ =                                                  \
                ((long long)ppb[j] * HWi + (long long)sy_ * Win + sx_) * 256; \
            dst[j] = ok_ ? in + off_ + csw : zeros + csw;                     \
        }                                                                     \
    } while (0)

#define ISSUE(APTR, T, KC, BUF)                                               \
    do {                                                                      \
        u16* dA_ = SMEM + (BUF)*16384;                                        \
        u16* dB_ = dA_ + 8192;                                                \
        _Pragma("unroll") for (int j = 0; j < 4; j++) {                       \
            GLD16(APTR[j] + (KC)*64, dA_ + (wid * 32 + j * 8) * 64);          \
            GLD16(wt + (T)*65536 + bofs[j] + (KC)*64,                         \
                  dB_ + (wid * 32 + j * 8) * 64);                             \
        }                                                                     \
    } while (0)

    f32x4 acc[4][4];
#pragma unroll
    for (int m = 0; m < 4; m++)
#pragma unroll
        for (int n = 0; n < 4; n++) acc[m][n] = (f32x4)0.f;

    const u16* aptrc[4];
    const u16* aptrn[4];
    MKPTR(aptrc, 0);
    ISSUE(aptrc, 0, 0, 0);

    const int rA = lane & 15;
    const int kb = (lane >> 4) * 8;
    const int xk = (rA & 7) << 3;

#pragma unroll 1
    for (int t = 0; t < 9; t++) {
        MKPTR(aptrn, t + 1);
#pragma unroll
        for (int kc = 0; kc < 4; kc++) {
            asm volatile("s_waitcnt vmcnt(0)" ::: "memory");
            __builtin_amdgcn_sched_barrier(0);
            __builtin_amdgcn_s_barrier();
            __builtin_amdgcn_sched_barrier(0);
            if (kc < 3) {
                ISSUE(aptrc, t, kc + 1, (kc + 1) & 1);
            } else if (t < 8) {
                ISSUE(aptrn, t + 1, 0, 0);
            }
            __builtin_amdgcn_sched_barrier(0);
            const u16* Ar = SMEM + (kc & 1) * 16384;
            const u16* Br = Ar + 8192;
#pragma unroll
            for (int kh = 0; kh < 2; kh++) {
                bf16x8 af[4], bfr[4];
#pragma unroll
                for (int m = 0; m < 4; m++)
                    af[m] = *(const bf16x8*)(Ar + (wr * 64 + m * 16 + rA) * 64 +
                                             ((kh * 32 + kb) ^ xk));
#pragma unroll
                for (int n = 0; n < 4; n++)
                    bfr[n] = *(const bf16x8*)(Br + (wc * 64 + n * 16 + rA) * 64 +
                                              ((kh * 32 + kb) ^ xk));
                __builtin_amdgcn_s_setprio(1);
#pragma unroll
                for (int m = 0; m < 4; m++)
#pragma unroll
                    for (int n = 0; n < 4; n++)
                        acc[m][n] = __builtin_amdgcn_mfma_f32_16x16x32_bf16(
                            af[m], bfr[n], acc[m][n], 0, 0, 0);
                __builtin_amdgcn_s_setprio(0);
            }
        }
#pragma unroll
        for (int j = 0; j < 4; j++) aptrc[j] = aptrn[j];
    }

    __syncthreads();
    float* ep = (float*)SMEM + wid * 2048;
    const int cb = n0 + wc * 64;
    float gms[4], bts[4];
#pragma unroll
    for (int n = 0; n < 4; n++) {
        gms[n] = gamma[cb + n * 16 + (lane & 15)];
        bts[n] = beta[cb + n * 16 + (lane & 15)];
    }
#pragma unroll
    for (int half = 0; half < 2; half++) {
#pragma unroll
        for (int m2 = 0; m2 < 2; m2++) {
            const int m = half * 2 + m2;
            const int lrb = m2 * 16 + ((lane >> 4) << 2);
            const int gpb = m0 + wr * 64 + half * 32 + lrb;
#pragma unroll
            for (int rr = 0; rr < 4; rr++) {
                float mk = 1.f;
                if (HAS_MASK) mk = (gpb + rr < M) ? mask[gpb + rr] : 0.f;
#pragma unroll
                for (int n = 0; n < 4; n++) {
                    float v = acc[m][n][rr] * gms[n] + bts[n];
                    if (HAS_MASK) v *= mk;
                    ep[(lrb + rr) * 64 + n * 16 + (lane & 15)] = v;
                }
            }
        }
#pragma unroll
        for (int i = 0; i < 8; i++) {
            const int lr = i * 4 + (lane >> 4);
            const int gp = m0 + wr * 64 + half * 32 + lr;
            f32x4 v = *(const f32x4*)(ep + lr * 64 + (lane & 15) * 4);
            if (HAS_RES && gp < M) {
                uint2 rv = *(const uint2*)(res + (size_t)gp * 256 + cb + (lane & 15) * 4);
                v[0] += b2f((u16)(rv.x & 0xffff));
                v[1] += b2f((u16)(rv.x >> 16));
                v[2] += b2f((u16)(rv.y & 0xffff));
                v[3] += b2f((u16)(rv.y >> 16));
            }
            v[0] = fmaxf(v[0], 0.f);
            v[1] = fmaxf(v[1], 0.f);
            v[2] = fmaxf(v[2], 0.f);
            v[3] = fmaxf(v[3], 0.f);
            if (HAS_F32OUT) *(f32x4*)(ep + lr * 64 + (lane & 15) * 4) = v;
            if (gp < M) {
                unsigned lo = (unsigned)f2b(v[0]) | ((unsigned)f2b(v[1]) << 16);
                unsigned hi = (unsigned)f2b(v[2]) | ((unsigned)f2b(v[3]) << 16);
                *(uint2*)(outb + (size_t)gp * 256 + cb + (lane & 15) * 4) =
                    make_uint2(lo, hi);
            }
        }
        if (HAS_F32OUT) {
#pragma unroll
            for (int i = 0; i < 16; i++) {
                const int lc = i * 4 + (lane >> 4);
                const int p0 = (lane & 15) * 2;
                const int gp0 = m0 + wr * 64 + half * 32 + p0;
                if (gp0 < M) {
                    float v0 = ep[p0 * 64 + lc];
                    float v1 = ep[(p0 + 1) * 64 + lc];
                    int b = gp0 / HWo;
                    int rr = gp0 - b * HWo;
                    const int ch = cb + lc;
                    float* o = outf + ((size_t)(b * 256 + ch)) * HWo + rr;
                    *(float2*)o = make_float2(v0, v1);
                }
            }
        }
    }
#undef MKPTR
#undef ISSUE
}

// ---------------------------------------------------------------------------
extern "C" void kernel_launch(void* const* d_in, const int* in_sizes, int n_in,
                              void* d_out, int out_size, void* d_ws,
                              size_t ws_size, hipStream_t stream) {
    const float* xyz = (const float*)d_in[0];
    const float* ptf = (const float*)d_in[1];
    const int* cnt = (const int*)d_in[2];
    const float* mw = (const float*)d_in[3];
    const float* mg = (const float*)d_in[4];
    const float* mb = (const float*)d_in[5];
    const float* c4w = (const float*)d_in[6];
    const float* c4g = (const float*)d_in[7];
    const float* c4b = (const float*)d_in[8];
    const float* c5w = (const float*)d_in[9];
    const float* c5g = (const float*)d_in[10];
    const float* c5b = (const float*)d_in[11];
    const int N = in_sizes[0] / 3;

    char* ws = (char*)d_ws;
    int* pcnt = (int*)ws;               //         0 :   282,752
    u16* zeros = (u16*)(ws + 282752);   //   282,752 :       512
    float* occ = (float*)(ws + 283264); //   283,264 :   282,752
    int* plist = (int*)(ws + 566016);   //   566,016 : 9,048,064
    u16* wt4 = (u16*)(ws + 9614080);
    u16* wt5 = (u16*)(ws + 15512320);
    u16* bufA = (u16*)(ws + 21410560);
    u16* bufB = (u16*)(ws + 57602816);
    u16* bufC = (u16*)(ws + 93795072);

    float* outXC4 = (float*)d_out;
    float* outY = ((float*)d_out) + 18096128;

    const int M94 = 2 * 94 * 94;

    hipMemsetAsync(ws, 0, 283264, stream);
    cvt_weights_kernel<<<90 * 16, 256, 0, stream>>>(c4w, c5w, wt4, wt5);
    bin_kernel<<<(N + 255) / 256, 256, 0, stream>>>(xyz, cnt, pcnt, plist, N);
    pillar_kernel<<<(2 * 188 * 188) / 4, 256, 0, stream>>>(
        xyz, ptf, mw, mg, mb, pcnt, plist, bufA, occ);

    dim3 gh188(3 * 94 * 2 * 2);   // tx=3, ty=94  -> 1128 blocks
    dim3 gh94(2 * 47 * 2 * 2);    // tx=2, ty=47  -> 376 blocks
    dim3 g94s2(2 * ((M94 + 127) / 128));
    const size_t WL = 9 * 65536;

    // conv4 @188 (stride 1, halo kernel)
    conv3x3_halo_kernel<true, false, false><<<gh188, 256, 0, stream>>>(
        bufA, wt4 + 0 * WL, zeros, c4g + 0, c4b + 0, occ, nullptr, bufB,
        nullptr, 188, 188, 3, 94);
    conv3x3_halo_kernel<true, false, false><<<gh188, 256, 0, stream>>>(
        bufB, wt4 + 1 * WL, zeros, c4g + 256, c4b + 256, occ, nullptr, bufC,
        nullptr, 188, 188, 3, 94);
    conv3x3_halo_kernel<true, true, false><<<gh188, 256, 0, stream>>>(
        bufC, wt4 + 2 * WL, zeros, c4g + 512, c4b + 512, occ, bufB, bufA,
        nullptr, 188, 188, 3, 94);
    conv3x3_halo_kernel<true, false, false><<<gh188, 256, 0, stream>>>(
        bufA, wt4 + 3 * WL, zeros, c4g + 768, c4b + 768, occ, nullptr, bufC,
        nullptr, 188, 188, 3, 94);
    conv3x3_halo_kernel<true, true, true><<<gh188, 256, 0, stream>>>(
        bufC, wt4 + 4 * WL, zeros, c4g + 1024, c4b + 1024, occ, bufA, bufB,
        outXC4, 188, 188, 3, 94);

    // conv5 layer 1: stride-2 (round-4 kernel)
    conv3x3_kernel<2, false, false, false><<<g94s2, 256, 0, stream>>>(
        bufB, wt5 + 0 * WL, zeros, c5g + 0, c5b + 0, nullptr, nullptr, bufA,
        nullptr, 188, 188, 94, 94, 2);
    // conv5 stride-1 layers @94 (halo kernel)
    conv3x3_halo_kernel<false, false, false><<<gh94, 256, 0, stream>>>(
        bufA, wt5 + 1 * WL, zeros, c5g + 256, c5b + 256, nullptr, nullptr,
        bufC, nullptr, 94, 94, 2, 47);
    conv3x3_halo_kernel<false, true, false><<<gh94, 256, 0, stream>>>(
        bufC, wt5 + 2 * WL, zeros, c5g + 512, c5b + 512, nullptr, bufA, bufB,
        nullptr, 94, 94, 2, 47);
    conv3x3_halo_kernel<false, false, false><<<gh94, 256, 0, stream>>>(
        bufB, wt5 + 3 * WL, zeros, c5g + 768, c5b + 768, nullptr, nullptr,
        bufC, nullptr, 94, 94, 2, 47);
    conv3x3_halo_kernel<false, true, true><<<gh94, 256, 0, stream>>>(
        bufC, wt5 + 4 * WL, zeros, c5g + 1024, c5b + 1024, nullptr, bufB,
        bufA, outY, 94, 94, 2, 47);
}

// Round 7
// 1190.148 us; speedup vs baseline: 1.2015x; 1.2015x over previous
//
#include <hip/hip_runtime.h>
#include <hip/hip_bf16.h>

// ---------------------------------------------------------------------------
// SpMiddlePillarEncoder8x18. Round 7: round-4 conv base + 3-buffer LDS ring
// with counted vmcnt(8) (T4): per step [issue stage(s+1); vmcnt(8); barrier;
// ds_read+MFMA]. Stage gets a full step of cover; no drain convoy. Stride-66
// epilogue pad (r6-validated). Halo kernel abandoned (B-reg latency flaw).
// ---------------------------------------------------------------------------

typedef __attribute__((ext_vector_type(8))) short bf16x8;
typedef __attribute__((ext_vector_type(4))) float f32x4;
typedef unsigned short u16;

#define GLD16(g, l)                                                   \
    __builtin_amdgcn_global_load_lds(                                 \
        (const __attribute__((address_space(1))) void*)(g),           \
        (__attribute__((address_space(3))) void*)(l), 16, 0, 0)

__device__ __forceinline__ u16 f2b(float f) {
    unsigned u = __float_as_uint(f);
    u += 0x7fffu + ((u >> 16) & 1u);  // round-to-nearest-even
    return (u16)(u >> 16);
}
__device__ __forceinline__ float b2f(u16 h) {
    return __uint_as_float(((unsigned)h) << 16);
}

// ------------------------------- binning -----------------------------------
__global__ __launch_bounds__(256) void bin_kernel(
    const float* __restrict__ xyz, const int* __restrict__ cnt,
    int* __restrict__ pcnt, int* __restrict__ plist, int N) {
    int i = blockIdx.x * 256 + threadIdx.x;
    if (i >= N) return;
    float x = xyz[3 * i], y = xyz[3 * i + 1];
    int b = (i < cnt[0]) ? 0 : 1;
    int ix = (int)floorf((x + 75.2f) / 0.8f);
    int iy = (int)floorf((y + 75.2f) / 0.8f);
    ix = min(max(ix, 0), 187);
    iy = min(max(iy, 0), 187);
    int flat = (b * 188 + iy) * 188 + ix;
    int slot = atomicAdd(pcnt + flat, 1);
    if (slot < 32) plist[flat * 32 + slot] = i;
}

// --------------------------- pillar MLP + max ------------------------------
__global__ __launch_bounds__(256) void pillar_kernel(
    const float* __restrict__ xyz, const float* __restrict__ ptf,
    const float* __restrict__ mw, const float* __restrict__ mg,
    const float* __restrict__ mb, const int* __restrict__ pcnt,
    const int* __restrict__ plist, u16* __restrict__ out,
    float* __restrict__ occ) {
    const int lane = threadIdx.x & 63, wid = threadIdx.x >> 6;
    const int p = blockIdx.x * 4 + wid;
    const int n = min(pcnt[p], 32);
    const int c = lane * 4;
    float m0 = 0.f, m1 = 0.f, m2 = 0.f, m3 = 0.f;
    if (n > 0) {
        const int ix = p % 188;
        const int iy = (p / 188) % 188;
        const float cx = -75.2f + ((float)ix + 0.5f) * 0.8f;
        const float cy = -75.2f + ((float)iy + 0.5f) * 0.8f;
        float4 w[8];
#pragma unroll
        for (int k = 0; k < 8; k++) w[k] = *(const float4*)(mw + k * 256 + c);
        for (int t = 0; t < n; t++) {
            int i = __builtin_amdgcn_readfirstlane(plist[p * 32 + t]);
            float x = xyz[3 * i], y = xyz[3 * i + 1], z = xyz[3 * i + 2];
            float f0 = ptf[2 * i], f1 = ptf[2 * i + 1];
            const float f[8] = {x, y, z, x - cx, y - cy, z, f0, f1};
            float s0 = 0.f, s1 = 0.f, s2 = 0.f, s3 = 0.f;
#pragma unroll
            for (int k = 0; k < 8; k++) {
                s0 = fmaf(f[k], w[k].x, s0);
                s1 = fmaf(f[k], w[k].y, s1);
                s2 = fmaf(f[k], w[k].z, s2);
                s3 = fmaf(f[k], w[k].w, s3);
            }
            float4 g4 = *(const float4*)(mg + c);
            float4 b4 = *(const float4*)(mb + c);
            m0 = fmaxf(m0, fmaxf(s0 * g4.x + b4.x, 0.f));
            m1 = fmaxf(m1, fmaxf(s1 * g4.y + b4.y, 0.f));
            m2 = fmaxf(m2, fmaxf(s2 * g4.z + b4.z, 0.f));
            m3 = fmaxf(m3, fmaxf(s3 * g4.w + b4.w, 0.f));
        }
    }
    unsigned lo = (unsigned)f2b(m0) | ((unsigned)f2b(m1) << 16);
    unsigned hi = (unsigned)f2b(m2) | ((unsigned)f2b(m3) << 16);
    *(uint2*)(out + (size_t)p * 256 + c) = make_uint2(lo, hi);
    if (lane == 0) occ[p] = (n > 0) ? 1.f : 0.f;
}

// -------------------- weight convert+transpose (once/launch) ---------------
__global__ void cvt_weights_kernel(const float* __restrict__ w4,
                                   const float* __restrict__ w5,
                                   u16* __restrict__ wt4,
                                   u16* __restrict__ wt5) {
    int bid = blockIdx.x;
    int mat = bid >> 4;
    int tile = bid & 15;
    int tr = tile >> 2, tc = tile & 3;
    const float* src = (mat < 45) ? (w4 + (size_t)mat * 65536)
                                  : (w5 + (size_t)(mat - 45) * 65536);
    u16* dst = (mat < 45) ? (wt4 + (size_t)mat * 65536)
                          : (wt5 + (size_t)(mat - 45) * 65536);
    __shared__ u16 sm[64][65];
    int tx = threadIdx.x & 63, ty = threadIdx.x >> 6;
#pragma unroll
    for (int k = 0; k < 64; k += 4) {
        int c = tr * 64 + ty + k;
        int n = tc * 64 + tx;
        sm[tx][ty + k] = f2b(src[c * 256 + n]);
    }
    __syncthreads();
#pragma unroll
    for (int k = 0; k < 64; k += 4) {
        int n = tc * 64 + ty + k;
        int c = tr * 64 + tx;
        dst[n * 256 + c] = sm[ty + k][tx];
    }
}

// ------------------------------ 3x3 conv -----------------------------------
// implicit GEMM: M = B*Hout*Wout, N = 256, K = 9*256. 128x128 tile, 4 waves,
// BK=64, 3-buffer LDS ring (96KB). Per step s:
//   issue stage(s+1)->buf[(s+1)%3]; s_waitcnt vmcnt(8); s_barrier;
//   ds_read buf[s%3] (XOR-swizzled); MFMA x32.
// Ring-3 safety: vmcnt(8) retires own stage(s) (in-order, 8 newer allowed)
// pre-barrier; stage(s+1)'s target was last read at step s-2 (barrier(s-1)
// proved done); concurrent readers touch the other two ring slots.
template <int STRIDE, bool HAS_MASK, bool HAS_RES, bool HAS_F32OUT>
__global__ __launch_bounds__(256) void conv3x3_kernel(
    const u16* __restrict__ in, const u16* __restrict__ wt,
    const u16* __restrict__ zeros, const float* __restrict__ gamma,
    const float* __restrict__ beta, const float* __restrict__ mask,
    const u16* __restrict__ res, u16* __restrict__ outb,
    float* __restrict__ outf, int Hin, int Win, int Hout, int Wout, int Bn) {
    const int M = Bn * Hout * Wout;
    const int HWo = Hout * Wout;
    const int HWi = Hin * Win;
    const int tid = threadIdx.x;
    const int lane = tid & 63, wid = tid >> 6;
    const int wr = wid >> 1, wc = wid & 1;
    const int nwg = gridDim.x;
    const int q = nwg >> 3, r = nwg & 7;
    const int xc = blockIdx.x & 7, jj = blockIdx.x >> 3;
    const int wg = (xc < r ? xc * (q + 1) : r * (q + 1) + (xc - r) * q) + jj;
    const int m0 = (wg >> 1) * 128;
    const int n0 = (wg & 1) * 128;

    __shared__ u16 SMEM[49152];  // 96 KiB: 3 x (As 16KB + Bs 16KB)
    const int lrow = lane >> 3;
    const int csw = (((lane & 7) ^ (lrow & 7)) << 3);

    int ppy[4], ppx[4], ppb[4];
    bool ppo[4];
#pragma unroll
    for (int j = 0; j < 4; j++) {
        int gp = m0 + wid * 32 + j * 8 + lrow;
        ppo[j] = gp < M;
        int g2 = ppo[j] ? gp : 0;
        int b = g2 / HWo;
        int rr = g2 - b * HWo;
        ppy[j] = rr / Wout;
        ppx[j] = rr - ppy[j] * Wout;
        ppb[j] = b;
    }
    int bofs[4];
#pragma unroll
    for (int j = 0; j < 4; j++)
        bofs[j] = (n0 + wid * 32 + j * 8 + lrow) * 256 + csw;

#define MKPTR(dst, T)                                                         \
    do {                                                                      \
        int dy_ = (T) / 3 - 1, dx_ = (T) % 3 - 1;                             \
        _Pragma("unroll") for (int j = 0; j < 4; j++) {                       \
            int sy_ = ppy[j] * STRIDE + dy_;                                  \
            int sx_ = ppx[j] * STRIDE + dx_;                                  \
            bool ok_ = ppo[j] && sy_ >= 0 && sy_ < Hin && sx_ >= 0 &&         \
                       sx_ < Win;                                             \
            long long off_ =                                                  \
                ((long long)ppb[j] * HWi + (long long)sy_ * Win + sx_) * 256; \
            dst[j] = ok_ ? in + off_ + csw : zeros + csw;                     \
        }                                                                     \
    } while (0)

#define ISSUE(APTR, T, KC, BUF)                                               \
    do {                                                                      \
        u16* dA_ = SMEM + (BUF)*16384;                                        \
        u16* dB_ = dA_ + 8192;                                                \
        _Pragma("unroll") for (int j = 0; j < 4; j++) {                       \
            GLD16(APTR[j] + (KC)*64, dA_ + (wid * 32 + j * 8) * 64);          \
            GLD16(wt + (T)*65536 + bofs[j] + (KC)*64,                         \
                  dB_ + (wid * 32 + j * 8) * 64);                             \
        }                                                                     \
    } while (0)

    f32x4 acc[4][4];
#pragma unroll
    for (int m = 0; m < 4; m++)
#pragma unroll
        for (int n = 0; n < 4; n++) acc[m][n] = (f32x4)0.f;

    const u16* aptrc[4];
    const u16* aptrn[4];
    MKPTR(aptrc, 0);
    ISSUE(aptrc, 0, 0, 0);  // stage(0) -> buf0

    const int rA = lane & 15;
    const int kb = (lane >> 4) * 8;
    const int xk = (rA & 7) << 3;
    int b0 = 0;  // = t % 3 (buffer index of step s = t*4+kc is (b0+kc)%3)

#pragma unroll 1
    for (int t = 0; t < 9; t++) {
        MKPTR(aptrn, t + 1);
#pragma unroll
        for (int kc = 0; kc < 4; kc++) {
            int ib = b0 + kc;
            if (ib >= 3) ib -= 3;
            int ibn = ib + 1;
            if (ibn >= 3) ibn -= 3;
            // issue stage(s+1) -> buf[(s+1)%3]
            if (kc < 3) {
                ISSUE(aptrc, t, kc + 1, ibn);
            } else if (t < 8) {
                ISSUE(aptrn, t + 1, 0, ibn);
            }
            __builtin_amdgcn_sched_barrier(0);
            // retire own stage(s): 8 newer loads (stage s+1) may stay in
            // flight; in-order completion => oldest 8 (stage s) are done.
            if (kc < 3 || t < 8) {
                asm volatile("s_waitcnt vmcnt(8)" ::: "memory");
            } else {
                asm volatile("s_waitcnt vmcnt(0)" ::: "memory");
            }
            __builtin_amdgcn_sched_barrier(0);
            __builtin_amdgcn_s_barrier();
            __builtin_amdgcn_sched_barrier(0);
            const u16* Ar = SMEM + ib * 16384;
            const u16* Br = Ar + 8192;
#pragma unroll
            for (int kh = 0; kh < 2; kh++) {
                bf16x8 af[4], bfr[4];
#pragma unroll
                for (int m = 0; m < 4; m++)
                    af[m] = *(const bf16x8*)(Ar + (wr * 64 + m * 16 + rA) * 64 +
                                             ((kh * 32 + kb) ^ xk));
#pragma unroll
                for (int n = 0; n < 4; n++)
                    bfr[n] = *(const bf16x8*)(Br + (wc * 64 + n * 16 + rA) * 64 +
                                              ((kh * 32 + kb) ^ xk));
                __builtin_amdgcn_s_setprio(1);
#pragma unroll
                for (int m = 0; m < 4; m++)
#pragma unroll
                    for (int n = 0; n < 4; n++)
                        acc[m][n] = __builtin_amdgcn_mfma_f32_16x16x32_bf16(
                            af[m], bfr[n], acc[m][n], 0, 0, 0);
                __builtin_amdgcn_s_setprio(0);
            }
        }
#pragma unroll
        for (int j = 0; j < 4; j++) aptrc[j] = aptrn[j];
        b0 = (b0 == 2) ? 0 : b0 + 1;
    }

    // ---------------- epilogue via LDS transpose (stride-66 pad) -----------
    __syncthreads();
    float* ep = (float*)SMEM + wid * 2112;  // 32 px x 66 f32 per wave
    const int cb = n0 + wc * 64;
    float gms[4], bts[4];
#pragma unroll
    for (int n = 0; n < 4; n++) {
        gms[n] = gamma[cb + n * 16 + rA];
        bts[n] = beta[cb + n * 16 + rA];
    }
#pragma unroll
    for (int half = 0; half < 2; half++) {
#pragma unroll
        for (int m2 = 0; m2 < 2; m2++) {
            const int m = half * 2 + m2;
            const int lrb = m2 * 16 + ((lane >> 4) << 2);
            const int gpb = m0 + wr * 64 + half * 32 + lrb;
#pragma unroll
            for (int rr = 0; rr < 4; rr++) {
                float mk = 1.f;
                if (HAS_MASK) mk = (gpb + rr < M) ? mask[gpb + rr] : 0.f;
#pragma unroll
                for (int n = 0; n < 4; n++) {
                    float v = acc[m][n][rr] * gms[n] + bts[n];
                    if (HAS_MASK) v *= mk;
                    ep[(lrb + rr) * 66 + n * 16 + rA] = v;
                }
            }
        }
#pragma unroll
        for (int i = 0; i < 8; i++) {
            const int lr = i * 4 + (lane >> 4);
            const int gp = m0 + wr * 64 + half * 32 + lr;
            f32x4 v = *(const f32x4*)(ep + lr * 66 + rA * 4);
            if (HAS_RES && gp < M) {
                uint2 rv = *(const uint2*)(res + (size_t)gp * 256 + cb + rA * 4);
                v[0] += b2f((u16)(rv.x & 0xffff));
                v[1] += b2f((u16)(rv.x >> 16));
                v[2] += b2f((u16)(rv.y & 0xffff));
                v[3] += b2f((u16)(rv.y >> 16));
            }
            v[0] = fmaxf(v[0], 0.f);
            v[1] = fmaxf(v[1], 0.f);
            v[2] = fmaxf(v[2], 0.f);
            v[3] = fmaxf(v[3], 0.f);
            if (HAS_F32OUT) *(f32x4*)(ep + lr * 66 + rA * 4) = v;
            if (gp < M) {
                unsigned lo = (unsigned)f2b(v[0]) | ((unsigned)f2b(v[1]) << 16);
                unsigned hi = (unsigned)f2b(v[2]) | ((unsigned)f2b(v[3]) << 16);
                *(uint2*)(outb + (size_t)gp * 256 + cb + rA * 4) =
                    make_uint2(lo, hi);
            }
        }
        if (HAS_F32OUT) {
#pragma unroll
            for (int i = 0; i < 16; i++) {
                const int lc = i * 4 + (lane >> 4);
                const int p0 = rA * 2;
                const int gp0 = m0 + wr * 64 + half * 32 + p0;
                if (gp0 < M) {
                    float v0 = ep[p0 * 66 + lc];
                    float v1 = ep[(p0 + 1) * 66 + lc];
                    int b = gp0 / HWo;
                    int rr = gp0 - b * HWo;
                    const int ch = cb + lc;
                    float* o = outf + ((size_t)(b * 256 + ch)) * HWo + rr;
                    *(float2*)o = make_float2(v0, v1);
                }
            }
        }
    }
#undef MKPTR
#undef ISSUE
}

// ---------------------------------------------------------------------------
extern "C" void kernel_launch(void* const* d_in, const int* in_sizes, int n_in,
                              void* d_out, int out_size, void* d_ws,
                              size_t ws_size, hipStream_t stream) {
    const float* xyz = (const float*)d_in[0];
    const float* ptf = (const float*)d_in[1];
    const int* cnt = (const int*)d_in[2];
    const float* mw = (const float*)d_in[3];
    const float* mg = (const float*)d_in[4];
    const float* mb = (const float*)d_in[5];
    const float* c4w = (const float*)d_in[6];
    const float* c4g = (const float*)d_in[7];
    const float* c4b = (const float*)d_in[8];
    const float* c5w = (const float*)d_in[9];
    const float* c5g = (const float*)d_in[10];
    const float* c5b = (const float*)d_in[11];
    const int N = in_sizes[0] / 3;

    char* ws = (char*)d_ws;
    int* pcnt = (int*)ws;               //         0 :   282,752
    u16* zeros = (u16*)(ws + 282752);   //   282,752 :       512
    float* occ = (float*)(ws + 283264); //   283,264 :   282,752
    int* plist = (int*)(ws + 566016);   //   566,016 : 9,048,064
    u16* wt4 = (u16*)(ws + 9614080);
    u16* wt5 = (u16*)(ws + 15512320);
    u16* bufA = (u16*)(ws + 21410560);
    u16* bufB = (u16*)(ws + 57602816);
    u16* bufC = (u16*)(ws + 93795072);

    float* outXC4 = (float*)d_out;
    float* outY = ((float*)d_out) + 18096128;

    const int M188 = 2 * 188 * 188;  // 70688
    const int M94 = 2 * 94 * 94;     // 17672

    hipMemsetAsync(ws, 0, 283264, stream);
    cvt_weights_kernel<<<90 * 16, 256, 0, stream>>>(c4w, c5w, wt4, wt5);
    bin_kernel<<<(N + 255) / 256, 256, 0, stream>>>(xyz, cnt, pcnt, plist, N);
    pillar_kernel<<<M188 / 4, 256, 0, stream>>>(xyz, ptf, mw, mg, mb, pcnt,
                                                plist, bufA, occ);

    dim3 g188(2 * ((M188 + 127) / 128)), g94(2 * ((M94 + 127) / 128));
    const size_t WL = 9 * 65536;

    // conv4 @188
    conv3x3_kernel<1, true, false, false><<<g188, 256, 0, stream>>>(
        bufA, wt4 + 0 * WL, zeros, c4g + 0, c4b + 0, occ, nullptr, bufB,
        nullptr, 188, 188, 188, 188, 2);
    conv3x3_kernel<1, true, false, false><<<g188, 256, 0, stream>>>(
        bufB, wt4 + 1 * WL, zeros, c4g + 256, c4b + 256, occ, nullptr, bufC,
        nullptr, 188, 188, 188, 188, 2);
    conv3x3_kernel<1, true, true, false><<<g188, 256, 0, stream>>>(
        bufC, wt4 + 2 * WL, zeros, c4g + 512, c4b + 512, occ, bufB, bufA,
        nullptr, 188, 188, 188, 188, 2);
    conv3x3_kernel<1, true, false, false><<<g188, 256, 0, stream>>>(
        bufA, wt4 + 3 * WL, zeros, c4g + 768, c4b + 768, occ, nullptr, bufC,
        nullptr, 188, 188, 188, 188, 2);
    conv3x3_kernel<1, true, true, true><<<g188, 256, 0, stream>>>(
        bufC, wt4 + 4 * WL, zeros, c4g + 1024, c4b + 1024, occ, bufA, bufB,
        outXC4, 188, 188, 188, 188, 2);

    // conv5 @94
    conv3x3_kernel<2, false, false, false><<<g94, 256, 0, stream>>>(
        bufB, wt5 + 0 * WL, zeros, c5g + 0, c5b + 0, nullptr, nullptr, bufA,
        nullptr, 188, 188, 94, 94, 2);
    conv3x3_kernel<1, false, false, false><<<g94, 256, 0, stream>>>(
        bufA, wt5 + 1 * WL, zeros, c5g + 256, c5b + 256, nullptr, nullptr,
        bufC, nullptr, 94, 94, 94, 94, 2);
    conv3x3_kernel<1, false, true, false><<<g94, 256, 0, stream>>>(
        bufC, wt5 + 2 * WL, zeros, c5g + 512, c5b + 512, nullptr, bufA, bufB,
        nullptr, 94, 94, 94, 94, 2);
    conv3x3_kernel<1, false, false, false><<<g94, 256, 0, stream>>>(
        bufB, wt5 + 3 * WL, zeros, c5g + 768, c5b + 768, nullptr, nullptr,
        bufC, nullptr, 94, 94, 94, 94, 2);
    conv3x3_kernel<1, false, true, true><<<g94, 256, 0, stream>>>(
        bufC, wt5 + 4 * WL, zeros, c5g + 1024, c5b + 1024, nullptr, bufB,
        bufA, outY, 94, 94, 94, 94, 2);
}

// Round 9
// 847.743 us; speedup vs baseline: 1.6867x; 1.4039x over previous
//
#include <hip/hip_runtime.h>
#include <hip/hip_bf16.h>

// ---------------------------------------------------------------------------
// SpMiddlePillarEncoder8x18. Round 9 = Round 8 with the A-ring slot index fix
// (r8 wrote slots 3..5 for t+kc>8 -> corrupted B buffers -> inf).
// Conv: 128x128 tile, BK=64, A ring-3 (48KB) + B dbuf (32KB) = 80KB ->
// 2 blocks/CU. Per step: wait vmcnt(4) [retires A(s),B(s), keeps A(s+1) in
// flight across the barrier]; barrier; issue B(s+1); issue A(s+2); compute.
// ---------------------------------------------------------------------------

typedef __attribute__((ext_vector_type(8))) short bf16x8;
typedef __attribute__((ext_vector_type(4))) float f32x4;
typedef unsigned short u16;

#define GLD16(g, l)                                                   \
    __builtin_amdgcn_global_load_lds(                                 \
        (const __attribute__((address_space(1))) void*)(g),           \
        (__attribute__((address_space(3))) void*)(l), 16, 0, 0)

__device__ __forceinline__ u16 f2b(float f) {
    unsigned u = __float_as_uint(f);
    u += 0x7fffu + ((u >> 16) & 1u);  // round-to-nearest-even
    return (u16)(u >> 16);
}
__device__ __forceinline__ float b2f(u16 h) {
    return __uint_as_float(((unsigned)h) << 16);
}

// ------------------------------- binning -----------------------------------
__global__ __launch_bounds__(256) void bin_kernel(
    const float* __restrict__ xyz, const int* __restrict__ cnt,
    int* __restrict__ pcnt, int* __restrict__ plist, int N) {
    int i = blockIdx.x * 256 + threadIdx.x;
    if (i >= N) return;
    float x = xyz[3 * i], y = xyz[3 * i + 1];
    int b = (i < cnt[0]) ? 0 : 1;
    int ix = (int)floorf((x + 75.2f) / 0.8f);
    int iy = (int)floorf((y + 75.2f) / 0.8f);
    ix = min(max(ix, 0), 187);
    iy = min(max(iy, 0), 187);
    int flat = (b * 188 + iy) * 188 + ix;
    int slot = atomicAdd(pcnt + flat, 1);
    if (slot < 32) plist[flat * 32 + slot] = i;
}

// --------------------------- pillar MLP + max ------------------------------
__global__ __launch_bounds__(256) void pillar_kernel(
    const float* __restrict__ xyz, const float* __restrict__ ptf,
    const float* __restrict__ mw, const float* __restrict__ mg,
    const float* __restrict__ mb, const int* __restrict__ pcnt,
    const int* __restrict__ plist, u16* __restrict__ out,
    float* __restrict__ occ) {
    const int lane = threadIdx.x & 63, wid = threadIdx.x >> 6;
    const int p = blockIdx.x * 4 + wid;
    const int n = min(pcnt[p], 32);
    const int c = lane * 4;
    float m0 = 0.f, m1 = 0.f, m2 = 0.f, m3 = 0.f;
    if (n > 0) {
        const int ix = p % 188;
        const int iy = (p / 188) % 188;
        const float cx = -75.2f + ((float)ix + 0.5f) * 0.8f;
        const float cy = -75.2f + ((float)iy + 0.5f) * 0.8f;
        float4 w[8];
#pragma unroll
        for (int k = 0; k < 8; k++) w[k] = *(const float4*)(mw + k * 256 + c);
        for (int t = 0; t < n; t++) {
            int i = __builtin_amdgcn_readfirstlane(plist[p * 32 + t]);
            float x = xyz[3 * i], y = xyz[3 * i + 1], z = xyz[3 * i + 2];
            float f0 = ptf[2 * i], f1 = ptf[2 * i + 1];
            const float f[8] = {x, y, z, x - cx, y - cy, z, f0, f1};
            float s0 = 0.f, s1 = 0.f, s2 = 0.f, s3 = 0.f;
#pragma unroll
            for (int k = 0; k < 8; k++) {
                s0 = fmaf(f[k], w[k].x, s0);
                s1 = fmaf(f[k], w[k].y, s1);
                s2 = fmaf(f[k], w[k].z, s2);
                s3 = fmaf(f[k], w[k].w, s3);
            }
            float4 g4 = *(const float4*)(mg + c);
            float4 b4 = *(const float4*)(mb + c);
            m0 = fmaxf(m0, fmaxf(s0 * g4.x + b4.x, 0.f));
            m1 = fmaxf(m1, fmaxf(s1 * g4.y + b4.y, 0.f));
            m2 = fmaxf(m2, fmaxf(s2 * g4.z + b4.z, 0.f));
            m3 = fmaxf(m3, fmaxf(s3 * g4.w + b4.w, 0.f));
        }
    }
    unsigned lo = (unsigned)f2b(m0) | ((unsigned)f2b(m1) << 16);
    unsigned hi = (unsigned)f2b(m2) | ((unsigned)f2b(m3) << 16);
    *(uint2*)(out + (size_t)p * 256 + c) = make_uint2(lo, hi);
    if (lane == 0) occ[p] = (n > 0) ? 1.f : 0.f;
}

// -------------------- weight convert+transpose (once/launch) ---------------
__global__ void cvt_weights_kernel(const float* __restrict__ w4,
                                   const float* __restrict__ w5,
                                   u16* __restrict__ wt4,
                                   u16* __restrict__ wt5) {
    int bid = blockIdx.x;
    int mat = bid >> 4;
    int tile = bid & 15;
    int tr = tile >> 2, tc = tile & 3;
    const float* src = (mat < 45) ? (w4 + (size_t)mat * 65536)
                                  : (w5 + (size_t)(mat - 45) * 65536);
    u16* dst = (mat < 45) ? (wt4 + (size_t)mat * 65536)
                          : (wt5 + (size_t)(mat - 45) * 65536);
    __shared__ u16 sm[64][65];
    int tx = threadIdx.x & 63, ty = threadIdx.x >> 6;
#pragma unroll
    for (int k = 0; k < 64; k += 4) {
        int c = tr * 64 + ty + k;
        int n = tc * 64 + tx;
        sm[tx][ty + k] = f2b(src[c * 256 + n]);
    }
    __syncthreads();
#pragma unroll
    for (int k = 0; k < 64; k += 4) {
        int n = tc * 64 + ty + k;
        int c = tr * 64 + tx;
        dst[n * 256 + c] = sm[ty + k][tx];
    }
}

// ------------------------------ 3x3 conv -----------------------------------
// implicit GEMM: M = B*Hout*Wout, N = 256, K = 9*256. 128x128 tile, 4 waves,
// BK=64. A ring-3 (slots 0..2) + B dbuf: 80KB -> 2 blocks/CU. Step s=t*4+kc:
//   wait vmcnt(4)  [A(s),B(s) retired; A(s+1) in flight]   (s=35: vmcnt(0))
//   s_barrier
//   issue B(s+1) -> Bbuf[(s+1)&1]; issue A(s+2) -> Aring[(s+2)%3]
//   compute(s): ds_read Aring[s%3], Bbuf[s&1]; 32 MFMA.
// Slot bookkeeping via b0 = t%3 (incremental), ib = (b0+kc) mod 3 == s%3
// since 4 == 1 (mod 3). [r8 bug: t+kc reduction overflowed to slots 3..5.]
template <int STRIDE, bool HAS_MASK, bool HAS_RES, bool HAS_F32OUT>
__global__ __launch_bounds__(256) void conv3x3_kernel(
    const u16* __restrict__ in, const u16* __restrict__ wt,
    const u16* __restrict__ zeros, const float* __restrict__ gamma,
    const float* __restrict__ beta, const float* __restrict__ mask,
    const u16* __restrict__ res, u16* __restrict__ outb,
    float* __restrict__ outf, int Hin, int Win, int Hout, int Wout, int Bn) {
    const int M = Bn * Hout * Wout;
    const int HWo = Hout * Wout;
    const int HWi = Hin * Win;
    const int tid = threadIdx.x;
    const int lane = tid & 63, wid = tid >> 6;
    const int wr = wid >> 1, wc = wid & 1;
    const int nwg = gridDim.x;
    const int q = nwg >> 3, r = nwg & 7;
    const int xc = blockIdx.x & 7, jj = blockIdx.x >> 3;
    const int wg = (xc < r ? xc * (q + 1) : r * (q + 1) + (xc - r) * q) + jj;
    const int m0 = (wg >> 1) * 128;
    const int n0 = (wg & 1) * 128;

    __shared__ u16 SMEM[40960];  // 80 KiB: A ring 3x16KB + B dbuf 2x16KB
    const int lrow = lane >> 3;
    const int csw = (((lane & 7) ^ (lrow & 7)) << 3);

    int ppy[4], ppx[4], ppb[4];
    bool ppo[4];
#pragma unroll
    for (int j = 0; j < 4; j++) {
        int gp = m0 + wid * 32 + j * 8 + lrow;
        ppo[j] = gp < M;
        int g2 = ppo[j] ? gp : 0;
        int b = g2 / HWo;
        int rr = g2 - b * HWo;
        ppy[j] = rr / Wout;
        ppx[j] = rr - ppy[j] * Wout;
        ppb[j] = b;
    }
    int bofs[4];
#pragma unroll
    for (int j = 0; j < 4; j++)
        bofs[j] = (n0 + wid * 32 + j * 8 + lrow) * 256 + csw;

#define MKPTR(dst, T)                                                         \
    do {                                                                      \
        int dy_ = (T) / 3 - 1, dx_ = (T) % 3 - 1;                             \
        _Pragma("unroll") for (int j = 0; j < 4; j++) {                       \
            int sy_ = ppy[j] * STRIDE + dy_;                                  \
            int sx_ = ppx[j] * STRIDE + dx_;                                  \
            bool ok_ = ppo[j] && sy_ >= 0 && sy_ < Hin && sx_ >= 0 &&         \
                       sx_ < Win;                                             \
            long long off_ =                                                  \
                ((long long)ppb[j] * HWi + (long long)sy_ * Win + sx_) * 256; \
            dst[j] = ok_ ? in + off_ + csw : zeros + csw;                     \
        }                                                                     \
    } while (0)

#define ISSUE_A(APTR, KC, SLOT)                                               \
    do {                                                                      \
        u16* dA_ = SMEM + (SLOT)*8192;                                        \
        _Pragma("unroll") for (int j = 0; j < 4; j++) {                       \
            GLD16(APTR[j] + (KC)*64, dA_ + (wid * 32 + j * 8) * 64);          \
        }                                                                     \
    } while (0)

#define ISSUE_B(T, KC, SLOT)                                                  \
    do {                                                                      \
        u16* dB_ = SMEM + 24576 + (SLOT)*8192;                                \
        _Pragma("unroll") for (int j = 0; j < 4; j++) {                       \
            GLD16(wt + (T)*65536 + bofs[j] + (KC)*64,                         \
                  dB_ + (wid * 32 + j * 8) * 64);                             \
        }                                                                     \
    } while (0)

    f32x4 acc[4][4];
#pragma unroll
    for (int m = 0; m < 4; m++)
#pragma unroll
        for (int n = 0; n < 4; n++) acc[m][n] = (f32x4)0.f;

    const u16* aptrc[4];
    const u16* aptrn[4];
    MKPTR(aptrc, 0);
    // prologue: A(0)->slot0, B(0)->buf0, A(1)->slot1  (12 loads outstanding)
    ISSUE_A(aptrc, 0, 0);
    ISSUE_B(0, 0, 0);
    ISSUE_A(aptrc, 1, 1);

    const int rA = lane & 15;
    const int kb = (lane >> 4) * 8;
    const int xk = (rA & 7) << 3;
    int b0 = 0;  // t % 3

#pragma unroll 1
    for (int t = 0; t < 9; t++) {
        MKPTR(aptrn, t + 1);
#pragma unroll
        for (int kc = 0; kc < 4; kc++) {
            const int s = t * 4 + kc;
            int ib = b0 + kc;            // s % 3  (4 == 1 mod 3)
            if (ib >= 3) ib -= 3;
            // wait: retire A(s)+B(s) (8 oldest of 12); keep A(s+1) in flight
            if (s < 35) {
                asm volatile("s_waitcnt vmcnt(4)" ::: "memory");
            } else {
                asm volatile("s_waitcnt vmcnt(0)" ::: "memory");
            }
            __builtin_amdgcn_sched_barrier(0);
            __builtin_amdgcn_s_barrier();
            __builtin_amdgcn_sched_barrier(0);
            // issue B(s+1) -> buffer read by compute(s-1) (done: barrier(s))
            if (s < 35) {
                if (kc < 3) {
                    ISSUE_B(t, kc + 1, (kc + 1) & 1);
                } else {
                    ISSUE_B(t + 1, 0, 0);
                }
            }
            // issue A(s+2) -> slot (s+2)%3, read by compute(s-1) (done)
            if (s < 34) {
                int ia = ib + 2;
                if (ia >= 3) ia -= 3;
                if (kc < 2) {
                    ISSUE_A(aptrc, kc + 2, ia);
                } else {
                    ISSUE_A(aptrn, kc - 2, ia);
                }
            }
            __builtin_amdgcn_sched_barrier(0);
            const u16* Ar = SMEM + ib * 8192;
            const u16* Br = SMEM + 24576 + (kc & 1) * 8192;
#pragma unroll
            for (int kh = 0; kh < 2; kh++) {
                bf16x8 af[4], bfr[4];
#pragma unroll
                for (int m = 0; m < 4; m++)
                    af[m] = *(const bf16x8*)(Ar + (wr * 64 + m * 16 + rA) * 64 +
                                             ((kh * 32 + kb) ^ xk));
#pragma unroll
                for (int n = 0; n < 4; n++)
                    bfr[n] = *(const bf16x8*)(Br + (wc * 64 + n * 16 + rA) * 64 +
                                              ((kh * 32 + kb) ^ xk));
                __builtin_amdgcn_s_setprio(1);
#pragma unroll
                for (int m = 0; m < 4; m++)
#pragma unroll
                    for (int n = 0; n < 4; n++)
                        acc[m][n] = __builtin_amdgcn_mfma_f32_16x16x32_bf16(
                            af[m], bfr[n], acc[m][n], 0, 0, 0);
                __builtin_amdgcn_s_setprio(0);
            }
        }
#pragma unroll
        for (int j = 0; j < 4; j++) aptrc[j] = aptrn[j];
        b0 = (b0 == 2) ? 0 : b0 + 1;
    }

    // ---------------- epilogue via LDS transpose (stride-66 pad) -----------
    __syncthreads();
    float* ep = (float*)SMEM + wid * 2112;  // 32 px x 66 f32 per wave
    const int cb = n0 + wc * 64;
    float gms[4], bts[4];
#pragma unroll
    for (int n = 0; n < 4; n++) {
        gms[n] = gamma[cb + n * 16 + rA];
        bts[n] = beta[cb + n * 16 + rA];
    }
#pragma unroll
    for (int half = 0; half < 2; half++) {
#pragma unroll
        for (int m2 = 0; m2 < 2; m2++) {
            const int m = half * 2 + m2;
            const int lrb = m2 * 16 + ((lane >> 4) << 2);
            const int gpb = m0 + wr * 64 + half * 32 + lrb;
#pragma unroll
            for (int rr = 0; rr < 4; rr++) {
                float mk = 1.f;
                if (HAS_MASK) mk = (gpb + rr < M) ? mask[gpb + rr] : 0.f;
#pragma unroll
                for (int n = 0; n < 4; n++) {
                    float v = acc[m][n][rr] * gms[n] + bts[n];
                    if (HAS_MASK) v *= mk;
                    ep[(lrb + rr) * 66 + n * 16 + rA] = v;
                }
            }
        }
#pragma unroll
        for (int i = 0; i < 8; i++) {
            const int lr = i * 4 + (lane >> 4);
            const int gp = m0 + wr * 64 + half * 32 + lr;
            f32x4 v = *(const f32x4*)(ep + lr * 66 + rA * 4);
            if (HAS_RES && gp < M) {
                uint2 rv = *(const uint2*)(res + (size_t)gp * 256 + cb + rA * 4);
                v[0] += b2f((u16)(rv.x & 0xffff));
                v[1] += b2f((u16)(rv.x >> 16));
                v[2] += b2f((u16)(rv.y & 0xffff));
                v[3] += b2f((u16)(rv.y >> 16));
            }
            v[0] = fmaxf(v[0], 0.f);
            v[1] = fmaxf(v[1], 0.f);
            v[2] = fmaxf(v[2], 0.f);
            v[3] = fmaxf(v[3], 0.f);
            if (HAS_F32OUT) *(f32x4*)(ep + lr * 66 + rA * 4) = v;
            if (gp < M) {
                unsigned lo = (unsigned)f2b(v[0]) | ((unsigned)f2b(v[1]) << 16);
                unsigned hi = (unsigned)f2b(v[2]) | ((unsigned)f2b(v[3]) << 16);
                *(uint2*)(outb + (size_t)gp * 256 + cb + rA * 4) =
                    make_uint2(lo, hi);
            }
        }
        if (HAS_F32OUT) {
#pragma unroll
            for (int i = 0; i < 16; i++) {
                const int lc = i * 4 + (lane >> 4);
                const int p0 = rA * 2;
                const int gp0 = m0 + wr * 64 + half * 32 + p0;
                if (gp0 < M) {
                    float v0 = ep[p0 * 66 + lc];
                    float v1 = ep[(p0 + 1) * 66 + lc];
                    int b = gp0 / HWo;
                    int rr = gp0 - b * HWo;
                    const int ch = cb + lc;
                    float* o = outf + ((size_t)(b * 256 + ch)) * HWo + rr;
                    *(float2*)o = make_float2(v0, v1);
                }
            }
        }
    }
#undef MKPTR
#undef ISSUE_A
#undef ISSUE_B
}

// ---------------------------------------------------------------------------
extern "C" void kernel_launch(void* const* d_in, const int* in_sizes, int n_in,
                              void* d_out, int out_size, void* d_ws,
                              size_t ws_size, hipStream_t stream) {
    const float* xyz = (const float*)d_in[0];
    const float* ptf = (const float*)d_in[1];
    const int* cnt = (const int*)d_in[2];
    const float* mw = (const float*)d_in[3];
    const float* mg = (const float*)d_in[4];
    const float* mb = (const float*)d_in[5];
    const float* c4w = (const float*)d_in[6];
    const float* c4g = (const float*)d_in[7];
    const float* c4b = (const float*)d_in[8];
    const float* c5w = (const float*)d_in[9];
    const float* c5g = (const float*)d_in[10];
    const float* c5b = (const float*)d_in[11];
    const int N = in_sizes[0] / 3;

    char* ws = (char*)d_ws;
    int* pcnt = (int*)ws;               //         0 :   282,752
    u16* zeros = (u16*)(ws + 282752);   //   282,752 :       512
    float* occ = (float*)(ws + 283264); //   283,264 :   282,752
    int* plist = (int*)(ws + 566016);   //   566,016 : 9,048,064
    u16* wt4 = (u16*)(ws + 9614080);
    u16* wt5 = (u16*)(ws + 15512320);
    u16* bufA = (u16*)(ws + 21410560);
    u16* bufB = (u16*)(ws + 57602816);
    u16* bufC = (u16*)(ws + 93795072);

    float* outXC4 = (float*)d_out;
    float* outY = ((float*)d_out) + 18096128;

    const int M188 = 2 * 188 * 188;  // 70688
    const int M94 = 2 * 94 * 94;     // 17672

    hipMemsetAsync(ws, 0, 283264, stream);
    cvt_weights_kernel<<<90 * 16, 256, 0, stream>>>(c4w, c5w, wt4, wt5);
    bin_kernel<<<(N + 255) / 256, 256, 0, stream>>>(xyz, cnt, pcnt, plist, N);
    pillar_kernel<<<M188 / 4, 256, 0, stream>>>(xyz, ptf, mw, mg, mb, pcnt,
                                                plist, bufA, occ);

    dim3 g188(2 * ((M188 + 127) / 128)), g94(2 * ((M94 + 127) / 128));
    const size_t WL = 9 * 65536;

    // conv4 @188
    conv3x3_kernel<1, true, false, false><<<g188, 256, 0, stream>>>(
        bufA, wt4 + 0 * WL, zeros, c4g + 0, c4b + 0, occ, nullptr, bufB,
        nullptr, 188, 188, 188, 188, 2);
    conv3x3_kernel<1, true, false, false><<<g188, 256, 0, stream>>>(
        bufB, wt4 + 1 * WL, zeros, c4g + 256, c4b + 256, occ, nullptr, bufC,
        nullptr, 188, 188, 188, 188, 2);
    conv3x3_kernel<1, true, true, false><<<g188, 256, 0, stream>>>(
        bufC, wt4 + 2 * WL, zeros, c4g + 512, c4b + 512, occ, bufB, bufA,
        nullptr, 188, 188, 188, 188, 2);
    conv3x3_kernel<1, true, false, false><<<g188, 256, 0, stream>>>(
        bufA, wt4 + 3 * WL, zeros, c4g + 768, c4b + 768, occ, nullptr, bufC,
        nullptr, 188, 188, 188, 188, 2);
    conv3x3_kernel<1, true, true, true><<<g188, 256, 0, stream>>>(
        bufC, wt4 + 4 * WL, zeros, c4g + 1024, c4b + 1024, occ, bufA, bufB,
        outXC4, 188, 188, 188, 188, 2);

    // conv5 @94
    conv3x3_kernel<2, false, false, false><<<g94, 256, 0, stream>>>(
        bufB, wt5 + 0 * WL, zeros, c5g + 0, c5b + 0, nullptr, nullptr, bufA,
        nullptr, 188, 188, 94, 94, 2);
    conv3x3_kernel<1, false, false, false><<<g94, 256, 0, stream>>>(
        bufA, wt5 + 1 * WL, zeros, c5g + 256, c5b + 256, nullptr, nullptr,
        bufC, nullptr, 94, 94, 94, 94, 2);
    conv3x3_kernel<1, false, true, false><<<g94, 256, 0, stream>>>(
        bufC, wt5 + 2 * WL, zeros, c5g + 512, c5b + 512, nullptr, bufA, bufB,
        nullptr, 94, 94, 94, 94, 2);
    conv3x3_kernel<1, false, false, false><<<g94, 256, 0, stream>>>(
        bufB, wt5 + 3 * WL, zeros, c5g + 768, c5b + 768, nullptr, nullptr,
        bufC, nullptr, 94, 94, 94, 94, 2);
    conv3x3_kernel<1, false, true, true><<<g94, 256, 0, stream>>>(
        bufC, wt5 + 4 * WL, zeros, c5g + 1024, c5b + 1024, nullptr, bufB,
        bufA, outY, 94, 94, 94, 94, 2);
}